// Round 13
// baseline (272.192 us; speedup 1.0000x reference)
//
#include <hip/hip_runtime.h>

// ---------------- problem constants ----------------
#define TSEQ  2048
#define NB    4
#define CDIM  1024
#define NHEAD 16
#define DH    64
#define MROWS (NB*TSEQ)   // 8192

using bf16x8 = __attribute__((ext_vector_type(8))) __bf16;
using f32x4  = __attribute__((ext_vector_type(4))) float;
using u16x8  = __attribute__((ext_vector_type(8))) unsigned short;
using u32x4  = __attribute__((ext_vector_type(4))) unsigned;

// fp32 -> bf16, round-to-nearest-even (bit-level)
__device__ __forceinline__ unsigned short f2bf(float x) {
  unsigned u = __float_as_uint(x);
  u += 0x7fffu + ((u >> 16) & 1u);
  return (unsigned short)(u >> 16);
}

// truncation pack via v_perm_b32: (lo,hi) -> bf16(lo) | bf16(hi)<<16, 1 instr.
__device__ __forceinline__ unsigned pkp(float lo, float hi) {
  return __builtin_amdgcn_perm(__float_as_uint(hi), __float_as_uint(lo), 0x07060302u);
}

// round-to-nearest (ties away) pack: 3 instrs / 2 floats; ~= RTNE for random data
__device__ __forceinline__ unsigned pk_rtn(float lo, float hi) {
  unsigned ua = __float_as_uint(lo) + 0x8000u;
  unsigned ub = __float_as_uint(hi) + 0x8000u;
  return __builtin_amdgcn_perm(ub, ua, 0x07060302u);
}

// raw hardware exp2 (proven rounds 6-12)
__device__ __forceinline__ float fexp2(float x) {
  float r;
  asm("v_exp_f32 %0, %1" : "=v"(r) : "v"(x));
  return r;
}

// async global->LDS, 16B per lane
__device__ __forceinline__ void gload_lds16(const void* g, void* l) {
  __builtin_amdgcn_global_load_lds(
      (const __attribute__((address_space(1))) void*)g,
      (__attribute__((address_space(3))) void*)l,
      16, 0, 0);
}

#define MFMA16(a, b, c) __builtin_amdgcn_mfma_f32_16x16x32_bf16((a), (b), (c), 0, 0, 0)

// ---------------- weight cast kernel (grid.y selects tensor) ----------------
__global__ void cast4_f32_bf16(const float* __restrict__ a, const float* __restrict__ b,
                               const float* __restrict__ c, const float* __restrict__ d,
                               unsigned short* __restrict__ out, int n) {
  const float* src = (blockIdx.y == 0) ? a : (blockIdx.y == 1) ? b
                   : (blockIdx.y == 2) ? c : d;
  int i = (blockIdx.x * 256 + threadIdx.x) * 8;
  if (i >= n) return;
  float4 x = *(const float4*)(src + i);
  float4 y = *(const float4*)(src + i + 4);
  u16x8 r;
  r[0] = f2bf(x.x); r[1] = f2bf(x.y); r[2] = f2bf(x.z); r[3] = f2bf(x.w);
  r[4] = f2bf(y.x); r[5] = f2bf(y.y); r[6] = f2bf(y.z); r[7] = f2bf(y.w);
  *(u16x8*)(out + (size_t)blockIdx.y * n + i) = r;
}

// ---------------- GEMM: C = A * B^T (round-12 proven; unchanged) ----------------
template<int MODE>
__global__ __launch_bounds__(256, 3)
void gemm_bt(const unsigned short* __restrict__ Abf,
             const float* __restrict__ Af0, const float* __restrict__ Af1,
             const float* __restrict__ Af2,
             const unsigned short* __restrict__ Bw,
             void* __restrict__ Cout,
             const float* __restrict__ bias,
             float qscale)
{
  constexpr int K  = CDIM;
  constexpr int BK = 64;
  __shared__ __attribute__((aligned(16))) unsigned short As[128 * BK];
  __shared__ __attribute__((aligned(16))) unsigned short Bs[128 * BK];

  const int tid = threadIdx.x;
  const int l   = tid & 63, w = tid >> 6;
  const int l16 = l & 15,  lq = l >> 4;
  const int wm  = w >> 1,  wn = w & 1;

  const int pz = (MODE == 0) ? blockIdx.z : 0;
  const float* Af = (MODE == 0)
      ? (pz == 0 ? Af0 : pz == 1 ? Af1 : Af2) : nullptr;
  Bw += (size_t)pz * CDIM * CDIM;
  const float oscale = (MODE == 0 && pz == 0) ? qscale : 1.0f;

  const int nwg  = gridDim.x * gridDim.y;
  const int orig = blockIdx.y * gridDim.x + blockIdx.x;
  const int wg   = (orig & 7) * (nwg >> 3) + (orig >> 3);
  const int m0   = (wg / gridDim.x) * 128, n0 = (wg % gridDim.x) * 128;

  f32x4 acc[4][4] = {};

  int srow[4], scol[4];
#pragma unroll
  for (int i = 0; i < 4; ++i) {
    int r = (i * 256 + tid) >> 3;
    srow[i] = r;
    scol[i] = (((tid & 7) ^ (r & 7)) << 3);
  }

  // MODE 0 pipeline state: packed A for the *current* K-step (16 regs)
  u32x4 apk[4];
  const float* aB[4];
  if constexpr (MODE == 0) {
#pragma unroll
    for (int i = 0; i < 4; ++i)
      aB[i] = Af + (size_t)(m0 + srow[i]) * K + scol[i];
    float4 ax[4], ay[4];
#pragma unroll
    for (int i = 0; i < 4; ++i) {
      ax[i] = *(const float4*)(aB[i]);
      ay[i] = *(const float4*)(aB[i] + 4);
    }
#pragma unroll
    for (int i = 0; i < 4; ++i) {
      apk[i][0] = pk_rtn(ax[i].x, ax[i].y); apk[i][1] = pk_rtn(ax[i].z, ax[i].w);
      apk[i][2] = pk_rtn(ay[i].x, ay[i].y); apk[i][3] = pk_rtn(ay[i].z, ay[i].w);
    }
  }

  for (int kt = 0; kt < K; kt += BK) {
    if constexpr (MODE == 0) {
#pragma unroll
      for (int i = 0; i < 4; ++i)
        *(u32x4*)((char*)As + (i * 256 + tid) * 16) = apk[i];
    } else {
#pragma unroll
      for (int i = 0; i < 4; ++i)
        gload_lds16(Abf + (size_t)(m0 + srow[i]) * K + kt + scol[i],
                    (char*)As + (i * 256 + w * 64) * 16);
    }
#pragma unroll
    for (int i = 0; i < 4; ++i)
      gload_lds16(Bw + (size_t)(n0 + srow[i]) * K + kt + scol[i],
                  (char*)Bs + (i * 256 + w * 64) * 16);
    __syncthreads();

    float4 ax[4], ay[4];
    if constexpr (MODE == 0) {
      if (kt + BK < K) {
#pragma unroll
        for (int i = 0; i < 4; ++i) {
          ax[i] = *(const float4*)(aB[i] + kt + BK);
          ay[i] = *(const float4*)(aB[i] + kt + BK + 4);
        }
      }
    }

#pragma unroll
    for (int kk = 0; kk < 2; ++kk) {
      bf16x8 af[4], bfr[4];
#pragma unroll
      for (int mi = 0; mi < 4; ++mi) {
        int row = wm * 64 + mi * 16 + l16;
        af[mi] = *(const bf16x8*)&As[row * BK + (((kk * 4 + lq) ^ (row & 7)) << 3)];
      }
#pragma unroll
      for (int nj = 0; nj < 4; ++nj) {
        int row = wn * 64 + nj * 16 + l16;
        bfr[nj] = *(const bf16x8*)&Bs[row * BK + (((kk * 4 + lq) ^ (row & 7)) << 3)];
      }
#pragma unroll
      for (int mi = 0; mi < 4; ++mi)
#pragma unroll
        for (int nj = 0; nj < 4; ++nj)
          acc[mi][nj] = MFMA16(af[mi], bfr[nj], acc[mi][nj]);
    }

    if constexpr (MODE == 0) {
      if (kt + BK < K) {
#pragma unroll
        for (int i = 0; i < 4; ++i) {
          apk[i][0] = pk_rtn(ax[i].x, ax[i].y); apk[i][1] = pk_rtn(ax[i].z, ax[i].w);
          apk[i][2] = pk_rtn(ay[i].x, ay[i].y); apk[i][3] = pk_rtn(ay[i].z, ay[i].w);
        }
      }
    }
    __syncthreads();
  }

#pragma unroll
  for (int mi = 0; mi < 4; ++mi) {
#pragma unroll
    for (int nj = 0; nj < 4; ++nj) {
      int gn = n0 + wn * 64 + nj * 16 + l16;
#pragma unroll
      for (int r = 0; r < 4; ++r) {
        int gm = m0 + wm * 64 + mi * 16 + lq * 4 + r;
        float v = acc[mi][nj][r];
        if constexpr (MODE == 0) {
          int b = gm >> 11, t = gm & (TSEQ - 1);
          int h = gn >> 6,  d = gn & 63;
          ((unsigned short*)Cout)[(size_t)pz * MROWS * CDIM +
              ((((size_t)b * NHEAD + h) * TSEQ + t) << 6) + d] = f2bf(v * oscale);
        } else {
          ((float*)Cout)[(size_t)gm * CDIM + gn] = v + bias[gn];
        }
      }
    }
  }
}

// ---------------- flash attention: QBLK=256, 8 waves (512 thr) ----------------
// Per-wave compute/layout identical to proven round-9 (each wave owns 32 q-rows,
// same fragment algebra, same V-ring sync). Changes: K-stage = ONE gload_lds per
// thread (512 x 16B = full tile); V staging on waves 0-3 only (guarded, formulas
// verbatim); grid 512 blocks (8 q-blocks x 64 bh), 2 blocks/CU.
__global__ __launch_bounds__(512, 4)
void attn_fwd(const unsigned short* __restrict__ Qh,
              const unsigned short* __restrict__ Kh,
              const unsigned short* __restrict__ Vh,
              unsigned short* __restrict__ O)
{
  __shared__ __attribute__((aligned(16))) unsigned short Ks[2][64 * DH];
  __shared__ __attribute__((aligned(16))) unsigned short Vt[3][DH * 64];

  const int tid = threadIdx.x;
  const int l   = tid & 63, w = tid >> 6;          // w in 0..7
  const int l16 = l & 15,  lq = l >> 4;
  const bool wlo = (tid < 256);                     // V-staging waves (uniform)

  // bijective XCD swizzle (512 blocks % 8 == 0); contiguous q-blocks per XCD
  const int orig    = blockIdx.y * gridDim.x + blockIdx.x;
  const int logical = (orig & 7) * 64 + (orig >> 3);
  const int bh  = logical >> 3;
  const int q0  = (logical & 7) * 256;
  const size_t base = (size_t)bh * TSEQ * DH;

  bf16x8 qfA0, qfA1, qfB0, qfB1;
  {
    const unsigned short* qp = Qh + base + (size_t)(q0 + w * 32 + l16) * DH + lq * 8;
    qfA0 = *(const bf16x8*)qp;
    qfA1 = *(const bf16x8*)(qp + 32);
    qfB0 = *(const bf16x8*)(qp + 16 * DH);
    qfB1 = *(const bf16x8*)(qp + 16 * DH + 32);
  }

  union { unsigned short u[8]; bf16x8 v; } onesu;
#pragma unroll
  for (int i = 0; i < 8; ++i) onesu.u[i] = 0x3F80;
  const bf16x8 ones = onesu.v;

  f32x4 oaccA[4] = {}, oaccB[4] = {};
  f32x4 laccA = {}, laccB = {};

  // V staging geometry (verbatim round-9 formulas; only threads 0..255 use it)
  const int vc  = tid & 7;
  const int vu  = (tid >> 3) & 31;
  const int kva = ((vu >> 4) << 5) | (vu & 15);
  const int vslot = ((vu >> 4) << 5) | (((vu >> 2) & 3) << 3) |
                    ((vu & 1) << 2) | (((vu >> 1) & 1) << 1);
  const int vvx = (vc << 10) | ((vslot << 1) ^ (vc << 4));

  const int kB0 = (l16 << 7) + ((lq ^ (l16 & 7)) << 4);
  const int kB1 = (l16 << 7) + (((4 + lq) ^ (l16 & 7)) << 4);

  int pvAddr[8];
#pragma unroll
  for (int dj = 0; dj < 4; ++dj) {
    int d  = dj * 16 + l16;
    int cx = (((d & 7) ^ (d >> 3)) & 7) << 4;
    pvAddr[dj * 2 + 0] = (((d << 6) + (lq << 3)) << 1) ^ cx;
    pvAddr[dj * 2 + 1] = (((d << 6) + 32 + (lq << 3)) << 1) ^ cx;
  }

  constexpr int TILE_STRIDE = 64 * DH;
  const int krow = tid >> 3;                        // 0..63: full tile, one load
  const int kcol = ((tid & 7) ^ (krow & 7)) << 3;
  const unsigned short* kPtr = Kh + base + (size_t)krow * DH + kcol;
  const unsigned short* vPtr = Vh + base + (size_t)kva * DH + vc * 8;

  auto stageK = [&](int kb) {
    gload_lds16(kPtr, (char*)Ks + kb * 8192 + w * 1024);   // dest byte = tid*16
  };
  auto loadV = [&](u16x8& v0, u16x8& v1) {
    v0 = *(const u16x8*)vPtr;
    v1 = *(const u16x8*)(vPtr + 16 * DH);
  };
  auto writeV = [&](int vb_i, u16x8 v0, u16x8 v1) {
    union { u16x8 v; unsigned u[4]; } a, b;
    a.v = v0; b.v = v1;
    char* vb = (char*)Vt + vb_i * 8192;
#pragma unroll
    for (int r = 0; r < 4; ++r) {
      unsigned w0 = __builtin_amdgcn_perm(b.u[r], a.u[r], 0x05040100u);
      unsigned w1 = __builtin_amdgcn_perm(b.u[r], a.u[r], 0x07060302u);
      int j0 = 2 * r, j1 = 2 * r + 1;
      *(unsigned*)(vb + ((vvx ^ (j0 << 4)) + j0 * 128)) = w0;
      *(unsigned*)(vb + ((vvx ^ (j1 << 4)) + j1 * 128)) = w1;
    }
  };

  bf16x8 peA0, peA1, peB0, peB1, poA0, poA1, poB0, poB1;

  // ---- prologue: V(0)->Vt[0], K(0)->Ks[0] ----
  {
    u16x8 v0, v1;
    if (wlo) loadV(v0, v1);
    stageK(0);
    if (wlo) writeV(0, v0, v1);
    kPtr += TILE_STRIDE; vPtr += TILE_STRIDE;
  }
  __syncthreads();

  // ---- t = 0: QK(0)+softmax -> pe; prefetch K(1)/V(1); writeV PRE-barrier ----
  {
    u16x8 nv0, nv1;
    if (wlo) loadV(nv0, nv1);
    stageK(1);
    kPtr += TILE_STRIDE; vPtr += TILE_STRIDE;

    const char* ksC = (const char*)Ks;
    f32x4 sA[4] = {}, sB[4] = {};
    __builtin_amdgcn_s_setprio(1);
#pragma unroll
    for (int nj = 0; nj < 4; ++nj) {
      bf16x8 kf0 = *(const bf16x8*)(ksC + nj * 2048 + kB0);
      bf16x8 kf1 = *(const bf16x8*)(ksC + nj * 2048 + kB1);
      sA[nj] = MFMA16(kf0, qfA0, sA[nj]); sA[nj] = MFMA16(kf1, qfA1, sA[nj]);
      sB[nj] = MFMA16(kf0, qfB0, sB[nj]); sB[nj] = MFMA16(kf1, qfB1, sB[nj]);
    }
    __builtin_amdgcn_s_setprio(0);
#pragma unroll
    for (int nj = 0; nj < 4; ++nj)
#pragma unroll
      for (int r = 0; r < 4; ++r) {
        sA[nj][r] = fexp2(sA[nj][r]);
        sB[nj][r] = fexp2(sB[nj][r]);
      }
    union { unsigned d[4]; bf16x8 v; } uA0, uA1, uB0, uB1;
    uA0.d[0] = pkp(sA[0][0], sA[1][0]); uA0.d[1] = pkp(sA[0][2], sA[1][2]);
    uA0.d[2] = pkp(sA[0][1], sA[1][1]); uA0.d[3] = pkp(sA[0][3], sA[1][3]);
    uA1.d[0] = pkp(sA[2][0], sA[3][0]); uA1.d[1] = pkp(sA[2][2], sA[3][2]);
    uA1.d[2] = pkp(sA[2][1], sA[3][1]); uA1.d[3] = pkp(sA[2][3], sA[3][3]);
    uB0.d[0] = pkp(sB[0][0], sB[1][0]); uB0.d[1] = pkp(sB[0][2], sB[1][2]);
    uB0.d[2] = pkp(sB[0][1], sB[1][1]); uB0.d[3] = pkp(sB[0][3], sB[1][3]);
    uB1.d[0] = pkp(sB[2][0], sB[3][0]); uB1.d[1] = pkp(sB[2][2], sB[3][2]);
    uB1.d[2] = pkp(sB[2][1], sB[3][1]); uB1.d[3] = pkp(sB[2][3], sB[3][3]);
    peA0 = uA0.v; peA1 = uA1.v; peB0 = uB0.v; peB1 = uB1.v;
    laccA = MFMA16(peA0, ones, laccA); laccA = MFMA16(peA1, ones, laccA);
    laccB = MFMA16(peB0, ones, laccB); laccB = MFMA16(peB1, ones, laccB);
    if (wlo) writeV(1, nv0, nv1);
    __syncthreads();
  }

  // ---- body: QK(t) | PV(t-1) | softmax(t); kb=t&1, vr=(t-1)%3, vw=(t+1)%3 ----
  auto body = [&](int kb, int vr, int vw, bool pf,
                  const bf16x8& rA0, const bf16x8& rA1, const bf16x8& rB0, const bf16x8& rB1,
                  bf16x8& wA0, bf16x8& wA1, bf16x8& wB0, bf16x8& wB1) {
    u16x8 nv0, nv1;
    if (pf) {
      if (wlo) loadV(nv0, nv1);
      stageK(kb ^ 1);
      kPtr += TILE_STRIDE; vPtr += TILE_STRIDE;
    }
    const char* ksC = (const char*)Ks + kb * 8192;
    const char* vtC = (const char*)Vt + vr * 8192;

    f32x4 sA[4] = {}, sB[4] = {};
    __builtin_amdgcn_s_setprio(1);
#pragma unroll
    for (int nj = 0; nj < 4; ++nj) {
      bf16x8 kf0 = *(const bf16x8*)(ksC + nj * 2048 + kB0);
      bf16x8 kf1 = *(const bf16x8*)(ksC + nj * 2048 + kB1);
      sA[nj] = MFMA16(kf0, qfA0, sA[nj]); sA[nj] = MFMA16(kf1, qfA1, sA[nj]);
      sB[nj] = MFMA16(kf0, qfB0, sB[nj]); sB[nj] = MFMA16(kf1, qfB1, sB[nj]);
    }
#pragma unroll
    for (int dj = 0; dj < 4; ++dj) {
      bf16x8 vf0 = *(const bf16x8*)(vtC + pvAddr[dj * 2 + 0]);
      bf16x8 vf1 = *(const bf16x8*)(vtC + pvAddr[dj * 2 + 1]);
      oaccA[dj] = MFMA16(rA0, vf0, oaccA[dj]); oaccA[dj] = MFMA16(rA1, vf1, oaccA[dj]);
      oaccB[dj] = MFMA16(rB0, vf0, oaccB[dj]); oaccB[dj] = MFMA16(rB1, vf1, oaccB[dj]);
    }
    __builtin_amdgcn_s_setprio(0);
#pragma unroll
    for (int nj = 0; nj < 4; ++nj)
#pragma unroll
      for (int r = 0; r < 4; ++r) {
        sA[nj][r] = fexp2(sA[nj][r]);
        sB[nj][r] = fexp2(sB[nj][r]);
      }
    union { unsigned d[4]; bf16x8 v; } uA0, uA1, uB0, uB1;
    uA0.d[0] = pkp(sA[0][0], sA[1][0]); uA0.d[1] = pkp(sA[0][2], sA[1][2]);
    uA0.d[2] = pkp(sA[0][1], sA[1][1]); uA0.d[3] = pkp(sA[0][3], sA[1][3]);
    uA1.d[0] = pkp(sA[2][0], sA[3][0]); uA1.d[1] = pkp(sA[2][2], sA[3][2]);
    uA1.d[2] = pkp(sA[2][1], sA[3][1]); uA1.d[3] = pkp(sA[2][3], sA[3][3]);
    uB0.d[0] = pkp(sB[0][0], sB[1][0]); uB0.d[1] = pkp(sB[0][2], sB[1][2]);
    uB0.d[2] = pkp(sB[0][1], sB[1][1]); uB0.d[3] = pkp(sB[0][3], sB[1][3]);
    uB1.d[0] = pkp(sB[2][0], sB[3][0]); uB1.d[1] = pkp(sB[2][2], sB[3][2]);
    uB1.d[2] = pkp(sB[2][1], sB[3][1]); uB1.d[3] = pkp(sB[2][3], sB[3][3]);
    wA0 = uA0.v; wA1 = uA1.v; wB0 = uB0.v; wB1 = uB1.v;
    laccA = MFMA16(wA0, ones, laccA); laccA = MFMA16(wA1, ones, laccA);
    laccB = MFMA16(wB0, ones, laccB); laccB = MFMA16(wB1, ones, laccB);
    if (pf && wlo) writeV(vw, nv0, nv1);
    __syncthreads();
  };

  for (int i = 0; i < 5; ++i) {
    body(1, 0, 2, true, peA0, peA1, peB0, peB1, poA0, poA1, poB0, poB1);
    body(0, 1, 0, true, poA0, poA1, poB0, poB1, peA0, peA1, peB0, peB1);
    body(1, 2, 1, true, peA0, peA1, peB0, peB1, poA0, poA1, poB0, poB1);
    body(0, 0, 2, true, poA0, poA1, poB0, poB1, peA0, peA1, peB0, peB1);
    body(1, 1, 0, true, peA0, peA1, peB0, peB1, poA0, poA1, poB0, poB1);
    body(0, 2, 1, true, poA0, poA1, poB0, poB1, peA0, peA1, peB0, peB1);
  }
  body(1, 0, 0, false, peA0, peA1, peB0, peB1, poA0, poA1, poB0, poB1);

  // ---- epilogue: PV(31) with P=po, V(31) in Vt[31%3 = 1] ----
  {
    const char* vtC = (const char*)Vt + 1 * 8192;
#pragma unroll
    for (int dj = 0; dj < 4; ++dj) {
      bf16x8 vf0 = *(const bf16x8*)(vtC + pvAddr[dj * 2 + 0]);
      bf16x8 vf1 = *(const bf16x8*)(vtC + pvAddr[dj * 2 + 1]);
      oaccA[dj] = MFMA16(poA0, vf0, oaccA[dj]); oaccA[dj] = MFMA16(poA1, vf1, oaccA[dj]);
      oaccB[dj] = MFMA16(poB0, vf0, oaccB[dj]); oaccB[dj] = MFMA16(poB1, vf1, oaccB[dj]);
    }
  }

  const int b = bh >> 4, h = bh & (NHEAD - 1);
#pragma unroll
  for (int r = 0; r < 4; ++r) {
    float invA = 1.f / laccA[r];
    float invB = 1.f / laccB[r];
    size_t obA = ((size_t)b * TSEQ + (q0 + w * 32 + lq * 4 + r)) * CDIM + h * DH;
    size_t obB = obA + (size_t)16 * CDIM;
#pragma unroll
    for (int dj = 0; dj < 4; ++dj) {
      O[obA + dj * 16 + l16] = f2bf(oaccA[dj][r] * invA);
      O[obB + dj * 16 + l16] = f2bf(oaccB[dj][r] * invB);
    }
  }
}

// ---------------- launch ----------------
extern "C" void kernel_launch(void* const* d_in, const int* in_sizes, int n_in,
                              void* d_out, int out_size, void* d_ws, size_t ws_size,
                              hipStream_t stream) {
  const float* q  = (const float*)d_in[0];
  const float* k  = (const float*)d_in[1];
  const float* v  = (const float*)d_in[2];
  const float* Wq = (const float*)d_in[3];
  const float* Wk = (const float*)d_in[4];
  const float* Wv = (const float*)d_in[5];
  const float* Wo = (const float*)d_in[6];
  const float* bo = (const float*)d_in[7];

  char* ws = (char*)d_ws;
  const size_t SZ_ACT = (size_t)MROWS * CDIM * 2;  // 16 MB
  const size_t SZ_W   = (size_t)CDIM * CDIM * 2;   //  2 MB
  unsigned short* wqb = (unsigned short*)(ws + 3 * SZ_ACT);
  unsigned short* wob = (unsigned short*)(ws + 3 * SZ_ACT + 3 * SZ_W);
  unsigned short* Qh  = (unsigned short*)(ws + 3 * SZ_ACT + 4 * SZ_W);
  unsigned short* Kh  = (unsigned short*)(ws + 4 * SZ_ACT + 4 * SZ_W);
  unsigned short* Vh  = (unsigned short*)(ws + 5 * SZ_ACT + 4 * SZ_W);
  unsigned short* AttO = (unsigned short*)ws;  // scratch region

  const int nW = CDIM * CDIM;    // 1048576

  cast4_f32_bf16<<<dim3(nW / 2048, 4), 256, 0, stream>>>(Wq, Wk, Wv, Wo, wqb, nW);

  const float QSCALE = 0.18033688011112042f;  // 0.125 * log2(e), folded into Qh

  gemm_bt<0><<<dim3(CDIM / 128, MROWS / 128, 3), 256, 0, stream>>>(
      nullptr, q, k, v, wqb, Qh, nullptr, QSCALE);

  attn_fwd<<<dim3(TSEQ / 256, NB * NHEAD), 512, 0, stream>>>(Qh, Kh, Vh, AttO);

  gemm_bt<1><<<dim3(CDIM / 128, MROWS / 128, 1), 256, 0, stream>>>(
      AttO, nullptr, nullptr, nullptr, wob, (float*)d_out, bo, 1.0f);
}

// Round 14
// 172.551 us; speedup vs baseline: 1.5775x; 1.5775x over previous
//
#include <hip/hip_runtime.h>

// ---------------- problem constants ----------------
#define TSEQ  2048
#define NB    4
#define CDIM  1024
#define NHEAD 16
#define DH    64
#define MROWS (NB*TSEQ)   // 8192

using bf16x8 = __attribute__((ext_vector_type(8))) __bf16;
using f32x4  = __attribute__((ext_vector_type(4))) float;
using u16x8  = __attribute__((ext_vector_type(8))) unsigned short;
using u32x4  = __attribute__((ext_vector_type(4))) unsigned;

// fp32 -> bf16, round-to-nearest-even (bit-level)
__device__ __forceinline__ unsigned short f2bf(float x) {
  unsigned u = __float_as_uint(x);
  u += 0x7fffu + ((u >> 16) & 1u);
  return (unsigned short)(u >> 16);
}

// truncation pack via v_perm_b32: (lo,hi) -> bf16(lo) | bf16(hi)<<16, 1 instr.
__device__ __forceinline__ unsigned pkp(float lo, float hi) {
  return __builtin_amdgcn_perm(__float_as_uint(hi), __float_as_uint(lo), 0x07060302u);
}

// round-to-nearest (ties away) pack: 3 instrs / 2 floats; ~= RTNE for random data
__device__ __forceinline__ unsigned pk_rtn(float lo, float hi) {
  unsigned ua = __float_as_uint(lo) + 0x8000u;
  unsigned ub = __float_as_uint(hi) + 0x8000u;
  return __builtin_amdgcn_perm(ub, ua, 0x07060302u);
}

// raw hardware exp2 (proven rounds 6-12)
__device__ __forceinline__ float fexp2(float x) {
  float r;
  asm("v_exp_f32 %0, %1" : "=v"(r) : "v"(x));
  return r;
}

// async global->LDS, 16B per lane
__device__ __forceinline__ void gload_lds16(const void* g, void* l) {
  __builtin_amdgcn_global_load_lds(
      (const __attribute__((address_space(1))) void*)g,
      (__attribute__((address_space(3))) void*)l,
      16, 0, 0);
}

#define MFMA16(a, b, c) __builtin_amdgcn_mfma_f32_16x16x32_bf16((a), (b), (c), 0, 0, 0)

// ---------------- weight cast kernel (grid.y selects tensor) ----------------
__global__ void cast4_f32_bf16(const float* __restrict__ a, const float* __restrict__ b,
                               const float* __restrict__ c, const float* __restrict__ d,
                               unsigned short* __restrict__ out, int n) {
  const float* src = (blockIdx.y == 0) ? a : (blockIdx.y == 1) ? b
                   : (blockIdx.y == 2) ? c : d;
  int i = (blockIdx.x * 256 + threadIdx.x) * 8;
  if (i >= n) return;
  float4 x = *(const float4*)(src + i);
  float4 y = *(const float4*)(src + i + 4);
  u16x8 r;
  r[0] = f2bf(x.x); r[1] = f2bf(x.y); r[2] = f2bf(x.z); r[3] = f2bf(x.w);
  r[4] = f2bf(y.x); r[5] = f2bf(y.y); r[6] = f2bf(y.z); r[7] = f2bf(y.w);
  *(u16x8*)(out + (size_t)blockIdx.y * n + i) = r;
}

// ---------------- GEMM: C = A * B^T (round-12 proven) ----------------
// MODE 0: fused QKV projections with in-kernel fp32->bf16 A-cast.
//         Pipeline per K-step: {ds_write packed A(kt) | B gload_lds | barrier |
//         issue A(kt+1) fp32 loads | 16 MFMA | convert A(kt+1)->packed | barrier}.
//         Only 16 packed regs (not 32 fp32) live across the barrier -> 3 waves/SIMD.
// MODE 1: A is bf16 (gload_lds path); writes fp32 C = acc + bias[n].
template<int MODE>
__global__ __launch_bounds__(256, 3)
void gemm_bt(const unsigned short* __restrict__ Abf,
             const float* __restrict__ Af0, const float* __restrict__ Af1,
             const float* __restrict__ Af2,
             const unsigned short* __restrict__ Bw,
             void* __restrict__ Cout,
             const float* __restrict__ bias,
             float qscale)
{
  constexpr int K  = CDIM;
  constexpr int BK = 64;
  __shared__ __attribute__((aligned(16))) unsigned short As[128 * BK];
  __shared__ __attribute__((aligned(16))) unsigned short Bs[128 * BK];

  const int tid = threadIdx.x;
  const int l   = tid & 63, w = tid >> 6;
  const int l16 = l & 15,  lq = l >> 4;
  const int wm  = w >> 1,  wn = w & 1;

  const int pz = (MODE == 0) ? blockIdx.z : 0;
  const float* Af = (MODE == 0)
      ? (pz == 0 ? Af0 : pz == 1 ? Af1 : Af2) : nullptr;
  Bw += (size_t)pz * CDIM * CDIM;
  const float oscale = (MODE == 0 && pz == 0) ? qscale : 1.0f;

  const int nwg  = gridDim.x * gridDim.y;
  const int orig = blockIdx.y * gridDim.x + blockIdx.x;
  const int wg   = (orig & 7) * (nwg >> 3) + (orig >> 3);
  const int m0   = (wg / gridDim.x) * 128, n0 = (wg % gridDim.x) * 128;

  f32x4 acc[4][4] = {};

  int srow[4], scol[4];
#pragma unroll
  for (int i = 0; i < 4; ++i) {
    int r = (i * 256 + tid) >> 3;
    srow[i] = r;
    scol[i] = (((tid & 7) ^ (r & 7)) << 3);
  }

  // MODE 0 pipeline state: packed A for the *current* K-step (16 regs)
  u32x4 apk[4];
  const float* aB[4];
  if constexpr (MODE == 0) {
#pragma unroll
    for (int i = 0; i < 4; ++i)
      aB[i] = Af + (size_t)(m0 + srow[i]) * K + scol[i];
    float4 ax[4], ay[4];
#pragma unroll
    for (int i = 0; i < 4; ++i) {
      ax[i] = *(const float4*)(aB[i]);
      ay[i] = *(const float4*)(aB[i] + 4);
    }
#pragma unroll
    for (int i = 0; i < 4; ++i) {
      apk[i][0] = pk_rtn(ax[i].x, ax[i].y); apk[i][1] = pk_rtn(ax[i].z, ax[i].w);
      apk[i][2] = pk_rtn(ay[i].x, ay[i].y); apk[i][3] = pk_rtn(ay[i].z, ay[i].w);
    }
  }

  for (int kt = 0; kt < K; kt += BK) {
    if constexpr (MODE == 0) {
      // wait-free: packed regs were finalized before the previous barrier
#pragma unroll
      for (int i = 0; i < 4; ++i)
        *(u32x4*)((char*)As + (i * 256 + tid) * 16) = apk[i];
    } else {
#pragma unroll
      for (int i = 0; i < 4; ++i)
        gload_lds16(Abf + (size_t)(m0 + srow[i]) * K + kt + scol[i],
                    (char*)As + (i * 256 + w * 64) * 16);
    }
#pragma unroll
    for (int i = 0; i < 4; ++i)
      gload_lds16(Bw + (size_t)(n0 + srow[i]) * K + kt + scol[i],
                  (char*)Bs + (i * 256 + w * 64) * 16);
    __syncthreads();

    // issue next A fp32 loads; they fly under the MFMA phase
    float4 ax[4], ay[4];
    if constexpr (MODE == 0) {
      if (kt + BK < K) {
#pragma unroll
        for (int i = 0; i < 4; ++i) {
          ax[i] = *(const float4*)(aB[i] + kt + BK);
          ay[i] = *(const float4*)(aB[i] + kt + BK + 4);
        }
      }
    }

#pragma unroll
    for (int kk = 0; kk < 2; ++kk) {
      bf16x8 af[4], bfr[4];
#pragma unroll
      for (int mi = 0; mi < 4; ++mi) {
        int row = wm * 64 + mi * 16 + l16;
        af[mi] = *(const bf16x8*)&As[row * BK + (((kk * 4 + lq) ^ (row & 7)) << 3)];
      }
#pragma unroll
      for (int nj = 0; nj < 4; ++nj) {
        int row = wn * 64 + nj * 16 + l16;
        bfr[nj] = *(const bf16x8*)&Bs[row * BK + (((kk * 4 + lq) ^ (row & 7)) << 3)];
      }
#pragma unroll
      for (int mi = 0; mi < 4; ++mi)
#pragma unroll
        for (int nj = 0; nj < 4; ++nj)
          acc[mi][nj] = MFMA16(af[mi], bfr[nj], acc[mi][nj]);
    }

    // convert BEFORE the barrier: vmcnt wait lands here (post-MFMA) either way,
    // and only the 16 packed regs survive across the barrier.
    if constexpr (MODE == 0) {
      if (kt + BK < K) {
#pragma unroll
        for (int i = 0; i < 4; ++i) {
          apk[i][0] = pk_rtn(ax[i].x, ax[i].y); apk[i][1] = pk_rtn(ax[i].z, ax[i].w);
          apk[i][2] = pk_rtn(ay[i].x, ay[i].y); apk[i][3] = pk_rtn(ay[i].z, ay[i].w);
        }
      }
    }
    __syncthreads();
  }

#pragma unroll
  for (int mi = 0; mi < 4; ++mi) {
#pragma unroll
    for (int nj = 0; nj < 4; ++nj) {
      int gn = n0 + wn * 64 + nj * 16 + l16;
#pragma unroll
      for (int r = 0; r < 4; ++r) {
        int gm = m0 + wm * 64 + mi * 16 + lq * 4 + r;
        float v = acc[mi][nj][r];
        if constexpr (MODE == 0) {
          int b = gm >> 11, t = gm & (TSEQ - 1);
          int h = gn >> 6,  d = gn & 63;
          ((unsigned short*)Cout)[(size_t)pz * MROWS * CDIM +
              ((((size_t)b * NHEAD + h) * TSEQ + t) << 6) + d] = f2bf(v * oscale);
        } else {
          ((float*)Cout)[(size_t)gm * CDIM + gn] = v + bias[gn];
        }
      }
    }
  }
}

// ---------------- flash attention (round-9/12 proven; QBLK=128, 4 waves) ------
// body(t): loadV/stageK(t+1) | QK(t) from Ks[t&1] | PV(t-1) from Vt[(t-1)%3]
//          | softmax(t)->P | lacc | writeV(t+1 -> Vt[(t+1)%3]) | barrier.
__global__ __launch_bounds__(256, 3)
void attn_fwd(const unsigned short* __restrict__ Qh,
              const unsigned short* __restrict__ Kh,
              const unsigned short* __restrict__ Vh,
              unsigned short* __restrict__ O)
{
  __shared__ __attribute__((aligned(16))) unsigned short Ks[2][64 * DH];
  __shared__ __attribute__((aligned(16))) unsigned short Vt[3][DH * 64];

  const int tid = threadIdx.x;
  const int l   = tid & 63, w = tid >> 6;
  const int l16 = l & 15,  lq = l >> 4;

  // bijective XCD swizzle (1024 blocks % 8 == 0)
  const int orig    = blockIdx.y * gridDim.x + blockIdx.x;
  const int logical = (orig & 7) * 128 + (orig >> 3);
  const int bh  = logical >> 4;
  const int q0  = (logical & 15) * 128;
  const size_t base = (size_t)bh * TSEQ * DH;

  bf16x8 qfA0, qfA1, qfB0, qfB1;
  {
    const unsigned short* qp = Qh + base + (size_t)(q0 + w * 32 + l16) * DH + lq * 8;
    qfA0 = *(const bf16x8*)qp;
    qfA1 = *(const bf16x8*)(qp + 32);
    qfB0 = *(const bf16x8*)(qp + 16 * DH);
    qfB1 = *(const bf16x8*)(qp + 16 * DH + 32);
  }

  union { unsigned short u[8]; bf16x8 v; } onesu;
#pragma unroll
  for (int i = 0; i < 8; ++i) onesu.u[i] = 0x3F80;
  const bf16x8 ones = onesu.v;

  f32x4 oaccA[4] = {}, oaccB[4] = {};
  f32x4 laccA = {}, laccB = {};

  const int vc  = tid & 7;
  const int vu  = tid >> 3;
  const int kva = ((vu >> 4) << 5) | (vu & 15);
  const int vslot = ((vu >> 4) << 5) | (((vu >> 2) & 3) << 3) |
                    ((vu & 1) << 2) | (((vu >> 1) & 1) << 1);
  const int vvx = (vc << 10) | ((vslot << 1) ^ (vc << 4));

  const int kB0 = (l16 << 7) + ((lq ^ (l16 & 7)) << 4);
  const int kB1 = (l16 << 7) + (((4 + lq) ^ (l16 & 7)) << 4);

  int pvAddr[8];
#pragma unroll
  for (int dj = 0; dj < 4; ++dj) {
    int d  = dj * 16 + l16;
    int cx = (((d & 7) ^ (d >> 3)) & 7) << 4;
    pvAddr[dj * 2 + 0] = (((d << 6) + (lq << 3)) << 1) ^ cx;
    pvAddr[dj * 2 + 1] = (((d << 6) + 32 + (lq << 3)) << 1) ^ cx;
  }

  constexpr int TILE_STRIDE = 64 * DH;
  const int krow = tid >> 3;
  const int kcol = ((tid & 7) ^ (krow & 7)) << 3;
  const unsigned short* kPtr = Kh + base + (size_t)krow * DH + kcol;
  const unsigned short* vPtr = Vh + base + (size_t)kva * DH + vc * 8;

  auto stageK = [&](int kb) {
    gload_lds16(kPtr,           (char*)Ks + kb * 8192 + (w * 64) * 16);
    gload_lds16(kPtr + 32 * DH, (char*)Ks + kb * 8192 + (256 + w * 64) * 16);
  };
  auto loadV = [&](u16x8& v0, u16x8& v1) {
    v0 = *(const u16x8*)vPtr;
    v1 = *(const u16x8*)(vPtr + 16 * DH);
  };
  auto writeV = [&](int vb_i, u16x8 v0, u16x8 v1) {
    union { u16x8 v; unsigned u[4]; } a, b;
    a.v = v0; b.v = v1;
    char* vb = (char*)Vt + vb_i * 8192;
#pragma unroll
    for (int r = 0; r < 4; ++r) {
      unsigned w0 = __builtin_amdgcn_perm(b.u[r], a.u[r], 0x05040100u);
      unsigned w1 = __builtin_amdgcn_perm(b.u[r], a.u[r], 0x07060302u);
      int j0 = 2 * r, j1 = 2 * r + 1;
      *(unsigned*)(vb + ((vvx ^ (j0 << 4)) + j0 * 128)) = w0;
      *(unsigned*)(vb + ((vvx ^ (j1 << 4)) + j1 * 128)) = w1;
    }
  };

  bf16x8 peA0, peA1, peB0, peB1, poA0, poA1, poB0, poB1;

  // ---- prologue: V(0)->Vt[0], K(0)->Ks[0] ----
  {
    u16x8 v0, v1;
    loadV(v0, v1);
    stageK(0);
    writeV(0, v0, v1);
    kPtr += TILE_STRIDE; vPtr += TILE_STRIDE;
  }
  __syncthreads();

  // ---- t = 0: QK(0)+softmax -> pe; prefetch K(1)/V(1); writeV PRE-barrier ----
  {
    u16x8 nv0, nv1;
    loadV(nv0, nv1);
    stageK(1);
    kPtr += TILE_STRIDE; vPtr += TILE_STRIDE;

    const char* ksC = (const char*)Ks;
    f32x4 sA[4] = {}, sB[4] = {};
    __builtin_amdgcn_s_setprio(1);
#pragma unroll
    for (int nj = 0; nj < 4; ++nj) {
      bf16x8 kf0 = *(const bf16x8*)(ksC + nj * 2048 + kB0);
      bf16x8 kf1 = *(const bf16x8*)(ksC + nj * 2048 + kB1);
      sA[nj] = MFMA16(kf0, qfA0, sA[nj]); sA[nj] = MFMA16(kf1, qfA1, sA[nj]);
      sB[nj] = MFMA16(kf0, qfB0, sB[nj]); sB[nj] = MFMA16(kf1, qfB1, sB[nj]);
    }
    __builtin_amdgcn_s_setprio(0);
#pragma unroll
    for (int nj = 0; nj < 4; ++nj)
#pragma unroll
      for (int r = 0; r < 4; ++r) {
        sA[nj][r] = fexp2(sA[nj][r]);
        sB[nj][r] = fexp2(sB[nj][r]);
      }
    union { unsigned d[4]; bf16x8 v; } uA0, uA1, uB0, uB1;
    uA0.d[0] = pkp(sA[0][0], sA[1][0]); uA0.d[1] = pkp(sA[0][2], sA[1][2]);
    uA0.d[2] = pkp(sA[0][1], sA[1][1]); uA0.d[3] = pkp(sA[0][3], sA[1][3]);
    uA1.d[0] = pkp(sA[2][0], sA[3][0]); uA1.d[1] = pkp(sA[2][2], sA[3][2]);
    uA1.d[2] = pkp(sA[2][1], sA[3][1]); uA1.d[3] = pkp(sA[2][3], sA[3][3]);
    uB0.d[0] = pkp(sB[0][0], sB[1][0]); uB0.d[1] = pkp(sB[0][2], sB[1][2]);
    uB0.d[2] = pkp(sB[0][1], sB[1][1]); uB0.d[3] = pkp(sB[0][3], sB[1][3]);
    uB1.d[0] = pkp(sB[2][0], sB[3][0]); uB1.d[1] = pkp(sB[2][2], sB[3][2]);
    uB1.d[2] = pkp(sB[2][1], sB[3][1]); uB1.d[3] = pkp(sB[2][3], sB[3][3]);
    peA0 = uA0.v; peA1 = uA1.v; peB0 = uB0.v; peB1 = uB1.v;
    laccA = MFMA16(peA0, ones, laccA); laccA = MFMA16(peA1, ones, laccA);
    laccB = MFMA16(peB0, ones, laccB); laccB = MFMA16(peB1, ones, laccB);
    writeV(1, nv0, nv1);
    __syncthreads();
  }

  // ---- body: QK(t) | PV(t-1) | softmax(t); kb=t&1, vr=(t-1)%3, vw=(t+1)%3 ----
  auto body = [&](int kb, int vr, int vw, bool pf,
                  const bf16x8& rA0, const bf16x8& rA1, const bf16x8& rB0, const bf16x8& rB1,
                  bf16x8& wA0, bf16x8& wA1, bf16x8& wB0, bf16x8& wB1) {
    u16x8 nv0, nv1;
    if (pf) {
      loadV(nv0, nv1);
      stageK(kb ^ 1);
      kPtr += TILE_STRIDE; vPtr += TILE_STRIDE;
    }
    const char* ksC = (const char*)Ks + kb * 8192;
    const char* vtC = (const char*)Vt + vr * 8192;

    f32x4 sA[4] = {}, sB[4] = {};
    __builtin_amdgcn_s_setprio(1);
#pragma unroll
    for (int nj = 0; nj < 4; ++nj) {
      bf16x8 kf0 = *(const bf16x8*)(ksC + nj * 2048 + kB0);
      bf16x8 kf1 = *(const bf16x8*)(ksC + nj * 2048 + kB1);
      sA[nj] = MFMA16(kf0, qfA0, sA[nj]); sA[nj] = MFMA16(kf1, qfA1, sA[nj]);
      sB[nj] = MFMA16(kf0, qfB0, sB[nj]); sB[nj] = MFMA16(kf1, qfB1, sB[nj]);
    }
#pragma unroll
    for (int dj = 0; dj < 4; ++dj) {
      bf16x8 vf0 = *(const bf16x8*)(vtC + pvAddr[dj * 2 + 0]);
      bf16x8 vf1 = *(const bf16x8*)(vtC + pvAddr[dj * 2 + 1]);
      oaccA[dj] = MFMA16(rA0, vf0, oaccA[dj]); oaccA[dj] = MFMA16(rA1, vf1, oaccA[dj]);
      oaccB[dj] = MFMA16(rB0, vf0, oaccB[dj]); oaccB[dj] = MFMA16(rB1, vf1, oaccB[dj]);
    }
    __builtin_amdgcn_s_setprio(0);
#pragma unroll
    for (int nj = 0; nj < 4; ++nj)
#pragma unroll
      for (int r = 0; r < 4; ++r) {
        sA[nj][r] = fexp2(sA[nj][r]);
        sB[nj][r] = fexp2(sB[nj][r]);
      }
    union { unsigned d[4]; bf16x8 v; } uA0, uA1, uB0, uB1;
    uA0.d[0] = pkp(sA[0][0], sA[1][0]); uA0.d[1] = pkp(sA[0][2], sA[1][2]);
    uA0.d[2] = pkp(sA[0][1], sA[1][1]); uA0.d[3] = pkp(sA[0][3], sA[1][3]);
    uA1.d[0] = pkp(sA[2][0], sA[3][0]); uA1.d[1] = pkp(sA[2][2], sA[3][2]);
    uA1.d[2] = pkp(sA[2][1], sA[3][1]); uA1.d[3] = pkp(sA[2][3], sA[3][3]);
    uB0.d[0] = pkp(sB[0][0], sB[1][0]); uB0.d[1] = pkp(sB[0][2], sB[1][2]);
    uB0.d[2] = pkp(sB[0][1], sB[1][1]); uB0.d[3] = pkp(sB[0][3], sB[1][3]);
    uB1.d[0] = pkp(sB[2][0], sB[3][0]); uB1.d[1] = pkp(sB[2][2], sB[3][2]);
    uB1.d[2] = pkp(sB[2][1], sB[3][1]); uB1.d[3] = pkp(sB[2][3], sB[3][3]);
    wA0 = uA0.v; wA1 = uA1.v; wB0 = uB0.v; wB1 = uB1.v;
    laccA = MFMA16(wA0, ones, laccA); laccA = MFMA16(wA1, ones, laccA);
    laccB = MFMA16(wB0, ones, laccB); laccB = MFMA16(wB1, ones, laccB);
    if (pf) writeV(vw, nv0, nv1);
    __syncthreads();
  };

  // t = 1..30: five 6-packs (indices literal; V(s) lives in Vt[s%3])
  for (int i = 0; i < 5; ++i) {
    body(1, 0, 2, true, peA0, peA1, peB0, peB1, poA0, poA1, poB0, poB1);
    body(0, 1, 0, true, poA0, poA1, poB0, poB1, peA0, peA1, peB0, peB1);
    body(1, 2, 1, true, peA0, peA1, peB0, peB1, poA0, poA1, poB0, poB1);
    body(0, 0, 2, true, poA0, poA1, poB0, poB1, peA0, peA1, peB0, peB1);
    body(1, 1, 0, true, peA0, peA1, peB0, peB1, poA0, poA1, poB0, poB1);
    body(0, 2, 1, true, poA0, poA1, poB0, poB1, peA0, peA1, peB0, peB1);
  }
  // t = 31: kb=1, vr=30%3=0, no prefetch
  body(1, 0, 0, false, peA0, peA1, peB0, peB1, poA0, poA1, poB0, poB1);

  // ---- epilogue: PV(31) with P=po, V(31) in Vt[31%3 = 1] ----
  {
    const char* vtC = (const char*)Vt + 1 * 8192;
#pragma unroll
    for (int dj = 0; dj < 4; ++dj) {
      bf16x8 vf0 = *(const bf16x8*)(vtC + pvAddr[dj * 2 + 0]);
      bf16x8 vf1 = *(const bf16x8*)(vtC + pvAddr[dj * 2 + 1]);
      oaccA[dj] = MFMA16(poA0, vf0, oaccA[dj]); oaccA[dj] = MFMA16(poA1, vf1, oaccA[dj]);
      oaccB[dj] = MFMA16(poB0, vf0, oaccB[dj]); oaccB[dj] = MFMA16(poB1, vf1, oaccB[dj]);
    }
  }

  // O /= l, write bf16 to [b][t][h*64+d]
  const int b = bh >> 4, h = bh & (NHEAD - 1);
#pragma unroll
  for (int r = 0; r < 4; ++r) {
    float invA = 1.f / laccA[r];
    float invB = 1.f / laccB[r];
    size_t obA = ((size_t)b * TSEQ + (q0 + w * 32 + lq * 4 + r)) * CDIM + h * DH;
    size_t obB = obA + (size_t)16 * CDIM;
#pragma unroll
    for (int dj = 0; dj < 4; ++dj) {
      O[obA + dj * 16 + l16] = f2bf(oaccA[dj][r] * invA);
      O[obB + dj * 16 + l16] = f2bf(oaccB[dj][r] * invB);
    }
  }
}

// ---------------- launch ----------------
extern "C" void kernel_launch(void* const* d_in, const int* in_sizes, int n_in,
                              void* d_out, int out_size, void* d_ws, size_t ws_size,
                              hipStream_t stream) {
  const float* q  = (const float*)d_in[0];
  const float* k  = (const float*)d_in[1];
  const float* v  = (const float*)d_in[2];
  const float* Wq = (const float*)d_in[3];
  const float* Wk = (const float*)d_in[4];
  const float* Wv = (const float*)d_in[5];
  const float* Wo = (const float*)d_in[6];
  const float* bo = (const float*)d_in[7];

  char* ws = (char*)d_ws;
  const size_t SZ_ACT = (size_t)MROWS * CDIM * 2;  // 16 MB
  const size_t SZ_W   = (size_t)CDIM * CDIM * 2;   //  2 MB
  unsigned short* wqb = (unsigned short*)(ws + 3 * SZ_ACT);
  unsigned short* wob = (unsigned short*)(ws + 3 * SZ_ACT + 3 * SZ_W);
  unsigned short* Qh  = (unsigned short*)(ws + 3 * SZ_ACT + 4 * SZ_W);
  unsigned short* Kh  = (unsigned short*)(ws + 4 * SZ_ACT + 4 * SZ_W);
  unsigned short* Vh  = (unsigned short*)(ws + 5 * SZ_ACT + 4 * SZ_W);
  unsigned short* AttO = (unsigned short*)ws;  // scratch region

  const int nW = CDIM * CDIM;    // 1048576

  // weight casts only (q/k/v casts fused into the QKV GEMM)
  cast4_f32_bf16<<<dim3(nW / 2048, 4), 256, 0, stream>>>(Wq, Wk, Wv, Wo, wqb, nW);

  const float QSCALE = 0.18033688011112042f;  // 0.125 * log2(e), folded into Qh

  // fused QKV projection with early-convert in-kernel A-cast
  gemm_bt<0><<<dim3(CDIM / 128, MROWS / 128, 3), 256, 0, stream>>>(
      nullptr, q, k, v, wqb, Qh, nullptr, QSCALE);

  attn_fwd<<<dim3(TSEQ / 128, NB * NHEAD), 256, 0, stream>>>(Qh, Kh, Vh, AttO);

  gemm_bt<1><<<dim3(CDIM / 128, MROWS / 128, 1), 256, 0, stream>>>(
      AttO, nullptr, nullptr, nullptr, wob, (float*)d_out, bo, 1.0f);
}